// Round 7
// baseline (74.735 us; speedup 1.0000x reference)
//
#include <hip/hip_runtime.h>
#include <math.h>

// Problem constants: B*T = 32768 rows, C=1, V=256, K=512 codes.
#define NV 256
#define NK 512
#define BM 64         // rows per block = 4 waves * 16
#define WM 16         // rows per wave (1 M-tile)
#define TSH 4096      // shorts per code-tile (16 codes * 256 dims, bf16)

typedef unsigned short u16;
typedef unsigned int u32;
using short8  = __attribute__((ext_vector_type(8))) short;
using floatx4 = __attribute__((ext_vector_type(4))) float;

// fp32 -> bf16 round-to-nearest-even.
__device__ __forceinline__ u16 f2bf(float f) {
    unsigned int u = __float_as_uint(f);
    u += 0x7fffu + ((u >> 16) & 1u);
    return (u16)(u >> 16);
}
__device__ __forceinline__ float bf2f(u16 h) {
    return __uint_as_float(((unsigned int)h) << 16);
}
__device__ __forceinline__ floatx4 mfma16(short8 a, short8 b, floatx4 c) {
    return __builtin_amdgcn_mfma_f32_16x16x32_bf16(a, b, c, 0, 0, 0);
}

// Kernel 0 (fused prep+cvt): per-code esq(+2.0 bias for positive-key argmin),
// bf16 codebook packed in MFMA-consumption order: shorts[tile][kc][code][8],
// so vq_main's load address is exactly base + lane*16 per (tile, kchunk).
__global__ __launch_bounds__(256) void vq_prepcvt(const float* __restrict__ emb,
                                                  float* __restrict__ esq1,
                                                  u16* __restrict__ ehws,
                                                  int* __restrict__ hist,
                                                  int* __restrict__ counter) {
    const int t = threadIdx.x;
    const int lane = t & 63;
    const int code = blockIdx.x * 4 + (t >> 6);   // one wave per code
    const int nt = code >> 4, c = code & 15;
    const float4 v = *(const float4*)(emb + (size_t)code * NV + lane * 4);
    ushort4 h;
    h.x = f2bf(v.x);
    h.y = f2bf(v.y);
    h.z = f2bf(v.z);
    h.w = f2bf(v.w);
    // dim base = lane*4 -> kchunk8 = lane>>1, j0 = (lane&1)*4
    const size_t base = (size_t)nt * TSH + (size_t)(lane >> 1) * 128 + c * 8 + (lane & 1) * 4;
    *(ushort4*)(ehws + base) = h;
    float s = v.x * v.x + v.y * v.y + v.z * v.z + v.w * v.w;
#pragma unroll
    for (int m = 1; m <= 32; m <<= 1) s += __shfl_xor(s, m, 64);
    if (lane == 0) esq1[code] = s + 2.0f;   // +2: keys provably positive
    const int g = blockIdx.x * 256 + t;
    if (g < NK) hist[g] = 0;
    if (g == 0) *counter = 0;
}

// Load one 16-code tile's B fragments straight from L2 into registers.
#define LOADT(R, T) do {                                                      \
    const u16* gp = bb + (size_t)(T) * TSH;                                   \
    _Pragma("unroll")                                                         \
    for (int ks = 0; ks < 8; ++ks) R[ks] = *(const short8*)(gp + ks * 512);   \
} while (0)

// One tile: 8 MFMAs in two independent chains + fused u32-key argmin.
#define COMPUTE(R, T) do {                                                    \
    floatx4 ae = {0.f, 0.f, 0.f, 0.f}, ao = {0.f, 0.f, 0.f, 0.f};             \
    ae = mfma16(ah[0], R[0], ae);  ao = mfma16(ah[1], R[1], ao);              \
    ae = mfma16(ah[2], R[2], ae);  ao = mfma16(ah[3], R[3], ao);              \
    ae = mfma16(ah[4], R[4], ae);  ao = mfma16(ah[5], R[5], ao);              \
    ae = mfma16(ah[6], R[6], ae);  ao = mfma16(ah[7], R[7], ao);              \
    const float evq = esq_lds[(T) * 16 + lr];                                 \
    const u32 code = (u32)((T) * 16 + lr);                                    \
    _Pragma("unroll")                                                         \
    for (int j = 0; j < 4; ++j) {                                             \
        float d = fmaf(-2.0f, ae[j] + ao[j], evq);  /* d+2 > 0 */             \
        u32 key = (__float_as_uint(d) & 0xfffffe00u) | code;                  \
        rmin[j] = min(rmin[j], key);                                          \
    }                                                                         \
} while (0)

// Kernel 1: MFMA nearest-code search + outputs + fused entropy (last block).
// 4 waves/block, 16 rows/wave, grid=512 (8 waves/CU). B streams directly
// from L2 via a 3-slot register pipeline: no LDS staging, no in-loop barriers.
__global__ __launch_bounds__(256, 2) void vq_main(
    const float* __restrict__ x,
    const float* __restrict__ emb,
    const u16* __restrict__ ehws,
    const float* __restrict__ esq1,
    int* __restrict__ hist,
    int* __restrict__ counter,
    float* __restrict__ out0,
    float* __restrict__ out1,
    float* __restrict__ out2,
    float* __restrict__ ent,
    int n_rows) {
    __shared__ float esq_lds[NK];
    __shared__ int idx_lds[BM];
    __shared__ int s_last;

    const int t = threadIdx.x;
    const int wid = t >> 6;
    const int lane = t & 63;
    const int lr = lane & 15;
    const int lg = lane >> 4;
    const size_t n0w = (size_t)blockIdx.x * BM + (size_t)wid * WM;
    const u16* bb = ehws + lane * 8;

    // ---- prologue: kick off first two B-tiles, then esq + A-frags ----
    short8 bA[8], bB[8], bC[8];
    LOADT(bA, 0);
    LOADT(bB, 1);

    esq_lds[t] = esq1[t];
    esq_lds[t + 256] = esq1[t + 256];

    // A fragments: 16 rows of x -> bf16 hi (search) + lo (epilogue only)
    short8 ah[8], al[8];
#pragma unroll
    for (int ks = 0; ks < 8; ++ks) {
        const float* p = x + (n0w + lr) * NV + ks * 32 + lg * 8;
        float4 u0 = *(const float4*)p;
        float4 u1 = *(const float4*)(p + 4);
        float f[8] = {u0.x, u0.y, u0.z, u0.w, u1.x, u1.y, u1.z, u1.w};
        short8 h, l;
#pragma unroll
        for (int j = 0; j < 8; ++j) {
            u16 hb = f2bf(f[j]);
            h[j] = (short)hb;
            l[j] = (short)f2bf(f[j] - bf2f(hb));
        }
        ah[ks] = h;
        al[ks] = l;
    }

    u32 rmin[4];
#pragma unroll
    for (int j = 0; j < 4; ++j) rmin[j] = 0xffffffffu;

    __syncthreads();   // esq_lds visible to all waves (only barrier pre-epilogue)

    // ---- main loop: 32 tiles, 3-slot register pipeline (2 tiles in flight) ----
    for (int tb = 0; tb < 30; tb += 3) {
        LOADT(bC, tb + 2);
        COMPUTE(bA, tb);
        LOADT(bA, tb + 3);
        COMPUTE(bB, tb + 1);
        LOADT(bB, tb + 4);
        COMPUTE(bC, tb + 2);
    }
    COMPUTE(bA, 30);
    COMPUTE(bB, 31);

    // ---- argmin across the 16 code-lanes (32-bit min) ----
#pragma unroll
    for (int j = 0; j < 4; ++j) {
#pragma unroll
        for (int m = 1; m <= 8; m <<= 1) {
            u32 v = (u32)__shfl_xor((int)rmin[j], m, 64);
            rmin[j] = min(rmin[j], v);
        }
    }
    if (lr == 0) {
#pragma unroll
        for (int j = 0; j < 4; ++j) {
            int i0 = (int)(rmin[j] & 511u);
            idx_lds[wid * WM + lg * 4 + j] = i0;   // acc row = lg*4+j
            atomicAdd(&hist[i0], 1);
        }
    }
    __syncthreads();

    // last-block election (hist adds of this block precede the fence+bump)
    if (t == 0) {
        __threadfence();
        s_last = (atomicAdd(counter, 1) == (int)gridDim.x - 1);
    }

    // ---- epilogue: gather e[idx]; x' = hi+lo reconstruction (err ~1e-5) ----
    const int idx = idx_lds[wid * WM + lr];
    float s0 = 0.0f;
#pragma unroll
    for (int ks = 0; ks < 8; ++ks) {
        const float* ep = emb + (size_t)idx * NV + ks * 32 + lg * 8;
        float4 e0 = *(const float4*)ep;
        float4 e1 = *(const float4*)(ep + 4);
        float ee[8] = {e0.x, e0.y, e0.z, e0.w, e1.x, e1.y, e1.z, e1.w};
        float ov[8];
#pragma unroll
        for (int j = 0; j < 8; ++j) {
            float xv = bf2f((u16)ah[ks][j]) + bf2f((u16)al[ks][j]);
            ov[j] = (ee[j] - xv) + xv;
            float d = xv - ee[j];
            s0 += d * d;
        }
        float* dst = out0 + (n0w + lr) * NV + ks * 32 + lg * 8;
        *(float4*)dst       = *(float4*)&ov[0];
        *(float4*)(dst + 4) = *(float4*)&ov[4];
    }
    s0 += __shfl_xor(s0, 16, 64);
    s0 += __shfl_xor(s0, 32, 64);
    if (lg == 0) {
        out1[n0w + lr] = s0;
        out2[n0w + lr] = s0;
    }

    // ---- fused entropy: the last block to finish computes it ----
    __syncthreads();
    if (s_last) {
        float local = 0.0f;
        const float invn = 1.0f / (float)n_rows;
        for (int k = t; k < NK; k += 256) {
            int h = atomicAdd(&hist[k], 0);   // device-coherent read
            if (h > 0) {
                float p = (float)h * invn;
                local += p * logf(p);
            }
        }
        // reuse esq_lds as reduction scratch
        esq_lds[t] = local;
        __syncthreads();
        for (int s = 128; s >= 1; s >>= 1) {
            if (t < s) esq_lds[t] += esq_lds[t + s];
            __syncthreads();
        }
        if (t == 0) *ent = -esq_lds[0];
    }
}

extern "C" void kernel_launch(void* const* d_in, const int* in_sizes, int n_in,
                              void* d_out, int out_size, void* d_ws, size_t ws_size,
                              hipStream_t stream) {
    const float* x   = (const float*)d_in[0];   // (B,T,1,256) fp32
    const float* emb = (const float*)d_in[1];   // (1,512,256) fp32

    const int n_rows = in_sizes[0] / NV;        // 32768

    float* out0 = (float*)d_out;
    float* out1 = out0 + (size_t)n_rows * NV;
    float* out2 = out1 + n_rows;
    float* ent  = out2 + n_rows;

    // workspace: esq+2 (2KB) | hist (2KB) | counter (16B) | packed bf16 codebook (256KB)
    float* esq1   = (float*)d_ws;
    int* hist     = (int*)(esq1 + NK);
    int* counter  = hist + NK;
    u16* ehws     = (u16*)(counter + 4);

    vq_prepcvt<<<NK / 4, 256, 0, stream>>>(emb, esq1, ehws, hist, counter);
    vq_main<<<n_rows / BM, 256, 0, stream>>>(x, emb, ehws, esq1, hist, counter,
                                             out0, out1, out2, ent, n_rows);
}

// Round 8
// 57.567 us; speedup vs baseline: 1.2982x; 1.2982x over previous
//
#include <hip/hip_runtime.h>
#include <math.h>

// Problem constants: B*T = 32768 rows, C=1, V=256, K=512 codes.
#define NV 256
#define NK 512
#define BM 64         // rows per block = 4 row-groups * 16
#define TSH 4096      // shorts per code-tile (16 codes * 256 dims, bf16)
#define TGSH 16384    // shorts per granule (4 tiles, 32 KB)
#define NPH 8         // phases (granules)

typedef unsigned short u16;
typedef unsigned int u32;
using short8  = __attribute__((ext_vector_type(8))) short;
using floatx4 = __attribute__((ext_vector_type(4))) float;

// fp32 -> bf16 round-to-nearest-even.
__device__ __forceinline__ u16 f2bf(float f) {
    unsigned int u = __float_as_uint(f);
    u += 0x7fffu + ((u >> 16) & 1u);
    return (u16)(u >> 16);
}
__device__ __forceinline__ float bf2f(u16 h) {
    return __uint_as_float(((unsigned int)h) << 16);
}
__device__ __forceinline__ floatx4 mfma16(short8 a, short8 b, floatx4 c) {
    return __builtin_amdgcn_mfma_f32_16x16x32_bf16(a, b, c, 0, 0, 0);
}
// async global -> LDS, 16B per lane. LDS dest = uniform base + lane*16.
__device__ __forceinline__ void gload_lds16(const u16* g, u16* l) {
    __builtin_amdgcn_global_load_lds(
        (const __attribute__((address_space(1))) void*)g,
        (__attribute__((address_space(3))) void*)l, 16, 0, 0);
}

// Kernel 0 (fused prep+cvt): per-code esq(+2.0 bias for positive-key argmin),
// bf16 codebook packed in MFMA-consumption order: shorts[tile][kc][code][8],
// so vq_main's ds_read address is exactly lane*16 (conflict-free, linear).
__global__ __launch_bounds__(256) void vq_prepcvt(const float* __restrict__ emb,
                                                  float* __restrict__ esq1,
                                                  u16* __restrict__ ehws,
                                                  int* __restrict__ hist,
                                                  int* __restrict__ counter) {
    const int t = threadIdx.x;
    const int lane = t & 63;
    const int code = blockIdx.x * 4 + (t >> 6);   // one wave per code
    const int nt = code >> 4, c = code & 15;
    const float4 v = *(const float4*)(emb + (size_t)code * NV + lane * 4);
    ushort4 h;
    h.x = f2bf(v.x);
    h.y = f2bf(v.y);
    h.z = f2bf(v.z);
    h.w = f2bf(v.w);
    // dim base = lane*4 -> kchunk8 = lane>>1, j0 = (lane&1)*4
    const size_t base = (size_t)nt * TSH + (size_t)(lane >> 1) * 128 + c * 8 + (lane & 1) * 4;
    *(ushort4*)(ehws + base) = h;
    float s = v.x * v.x + v.y * v.y + v.z * v.z + v.w * v.w;
#pragma unroll
    for (int m = 1; m <= 32; m <<= 1) s += __shfl_xor(s, m, 64);
    if (lane == 0) esq1[code] = s + 2.0f;   // +2: keys provably positive
    const int g = blockIdx.x * 256 + t;
    if (g < NK) hist[g] = 0;
    if (g == 0) *counter = 0;
}

// Kernel 1: MFMA nearest-code search + outputs + fused entropy (last block).
// 512 threads = 8 waves = 4 row-groups x 2 code-halves; grid=512
// -> 16 waves/CU = 4 waves/SIMD (code-split doubles TLP at identical
// per-CU LDS/MFMA/staging volume). Double-buffered 32KB granules staged
// via global_load_lds, counted vmcnt(4), raw s_barrier (never drains vmcnt).
__global__ __launch_bounds__(512, 4) void vq_main(
    const float* __restrict__ x,
    const float* __restrict__ emb,
    const u16* __restrict__ ehws,
    const float* __restrict__ esq1,
    int* __restrict__ hist,
    int* __restrict__ counter,
    float* __restrict__ out0,
    float* __restrict__ out1,
    float* __restrict__ out2,
    float* __restrict__ ent,
    int n_rows) {
    __shared__ u16 lds_b[2 * TGSH];       // 64 KB
    __shared__ float esq_lds[NK];         // 2 KB (reused as entropy scratch)
    __shared__ u32 kmin[8][16];
    __shared__ int idx_lds[BM];
    __shared__ int s_last;

    const int t = threadIdx.x;
    const int wid = t >> 6;
    const int lane = t & 63;
    const int lr = lane & 15;
    const int lg = lane >> 4;
    const int rg = wid >> 1;      // row-group 0..3
    const int half = wid & 1;     // code-half 0/1
    const size_t n0w = (size_t)blockIdx.x * BM + (size_t)rg * 16;

    // Stage one 32KB granule (4 tiles): 4 loads/thread at 512 threads.
#define STAGE(B, P) do {                                             \
        const u16* gs = ehws + (size_t)(P) * TGSH + t * 8;           \
        u16* lb = &lds_b[(B) * TGSH + t * 8];                        \
        gload_lds16(gs,         lb);                                 \
        gload_lds16(gs +  4096, lb +  4096);                         \
        gload_lds16(gs +  8192, lb +  8192);                         \
        gload_lds16(gs + 12288, lb + 12288);                         \
    } while (0)

    // ---- prologue: issue granule 0, then esq + A-frags under that latency ----
    STAGE(0, 0);

    esq_lds[t] = esq1[t];   // 512 threads cover NK

    // A fragments: 16 rows of x -> bf16 hi only (search); epilogue re-reads x.
    short8 ah[8];
#pragma unroll
    for (int ks = 0; ks < 8; ++ks) {
        const float* p = x + (n0w + lr) * NV + ks * 32 + lg * 8;
        float4 u0 = *(const float4*)p;
        float4 u1 = *(const float4*)(p + 4);
        float f[8] = {u0.x, u0.y, u0.z, u0.w, u1.x, u1.y, u1.z, u1.w};
        short8 h;
#pragma unroll
        for (int j = 0; j < 8; ++j) h[j] = (short)f2bf(f[j]);
        ah[ks] = h;
    }

    u32 rmin[4];
#pragma unroll
    for (int j = 0; j < 4; ++j) rmin[j] = 0xffffffffu;

    __syncthreads();   // esq_lds + granule 0 visible to all waves

    // ---- main loop: 8 phases; each wave computes 2 of the granule's 4 tiles ----
#pragma unroll 2
    for (int p = 0; p < NPH; ++p) {
        // prefetch next granule (dummy-clamp keeps vmcnt count uniform;
        // the re-staged buffer at p=7 is never read)
        const int pn = (p + 1 < NPH) ? (p + 1) : (NPH - 1);
        STAGE((p + 1) & 1, pn);
        // granule p fully landed for this wave (4 outstanding = next granule)
        asm volatile("s_waitcnt vmcnt(4) lgkmcnt(0)" ::: "memory");
        __builtin_amdgcn_s_barrier();     // ...and for every other wave's share
        asm volatile("" ::: "memory");

        const u16* gb = &lds_b[(p & 1) * TGSH];
        __builtin_amdgcn_s_setprio(1);
#pragma unroll
        for (int tt = 0; tt < 2; ++tt) {
            const int lt = half * 2 + tt;           // tile-in-granule 0..3
            const int nt = 4 * p + lt;              // global code tile
            const u16* bb = gb + lt * TSH + lane * 8;
            floatx4 ae = {0.f, 0.f, 0.f, 0.f}, ao = {0.f, 0.f, 0.f, 0.f};
            short8 b0 = *(const short8*)(bb);
            short8 b1 = *(const short8*)(bb + 512);
            short8 b2 = *(const short8*)(bb + 1024);
            short8 b3 = *(const short8*)(bb + 1536);
            short8 b4 = *(const short8*)(bb + 2048);
            short8 b5 = *(const short8*)(bb + 2560);
            short8 b6 = *(const short8*)(bb + 3072);
            short8 b7 = *(const short8*)(bb + 3584);
            ae = mfma16(ah[0], b0, ae);  ao = mfma16(ah[1], b1, ao);
            ae = mfma16(ah[2], b2, ae);  ao = mfma16(ah[3], b3, ao);
            ae = mfma16(ah[4], b4, ae);  ao = mfma16(ah[5], b5, ao);
            ae = mfma16(ah[6], b6, ae);  ao = mfma16(ah[7], b7, ao);
            const float evq = esq_lds[nt * 16 + lr];   // esq + 2.0
            const u32 code = (u32)(nt * 16 + lr);
#pragma unroll
            for (int j = 0; j < 4; ++j) {
                // d+2 = (esq+2) - 2*cross > 0 -> raw float bits are monotone
                float d = fmaf(-2.0f, ae[j] + ao[j], evq);
                u32 key = (__float_as_uint(d) & 0xfffffe00u) | code;
                rmin[j] = min(rmin[j], key);
            }
        }
        __builtin_amdgcn_s_setprio(0);

        // all waves finished reading this buffer before next phase overwrites it
        asm volatile("s_waitcnt lgkmcnt(0)" ::: "memory");
        __builtin_amdgcn_s_barrier();
        asm volatile("" ::: "memory");
    }
#undef STAGE

    // ---- argmin across the 16 code-lanes (32-bit min), then cross-half ----
#pragma unroll
    for (int j = 0; j < 4; ++j) {
#pragma unroll
        for (int m = 1; m <= 8; m <<= 1) {
            u32 v = (u32)__shfl_xor((int)rmin[j], m, 64);
            rmin[j] = min(rmin[j], v);
        }
    }
    if (lr == 0) {
#pragma unroll
        for (int j = 0; j < 4; ++j) kmin[wid][lg * 4 + j] = rmin[j];  // row=lg*4+j
    }
    __syncthreads();
    if (t < BM) {
        const int rg2 = t >> 4, r = t & 15;
        u32 key = min(kmin[rg2 * 2][r], kmin[rg2 * 2 + 1][r]);
        const int idx = (int)(key & 511u);
        idx_lds[t] = idx;
        atomicAdd(&hist[idx], 1);
    }
    __syncthreads();

    // last-block election (this block's hist adds precede the fence+bump)
    if (t == 0) {
        __threadfence();
        s_last = (atomicAdd(counter, 1) == (int)gridDim.x - 1);
    }

    // ---- epilogue (half-0 waves): gather e[idx], exact fp32 x re-read ----
    if (half == 0) {
        const int idx = idx_lds[rg * 16 + lr];
        float s0 = 0.0f;
#pragma unroll
        for (int ks = 0; ks < 8; ++ks) {
            const float* xp = x + (n0w + lr) * NV + ks * 32 + lg * 8;
            const float* ep = emb + (size_t)idx * NV + ks * 32 + lg * 8;
            float4 x0v = *(const float4*)xp;
            float4 x1v = *(const float4*)(xp + 4);
            float4 e0 = *(const float4*)ep;
            float4 e1 = *(const float4*)(ep + 4);
            float xx[8] = {x0v.x, x0v.y, x0v.z, x0v.w, x1v.x, x1v.y, x1v.z, x1v.w};
            float ee[8] = {e0.x, e0.y, e0.z, e0.w, e1.x, e1.y, e1.z, e1.w};
            float ov[8];
#pragma unroll
            for (int j = 0; j < 8; ++j) {
                ov[j] = (ee[j] - xx[j]) + xx[j];
                float d = xx[j] - ee[j];
                s0 += d * d;
            }
            float* dst = out0 + (n0w + lr) * NV + ks * 32 + lg * 8;
            *(float4*)dst       = *(float4*)&ov[0];
            *(float4*)(dst + 4) = *(float4*)&ov[4];
        }
        s0 += __shfl_xor(s0, 16, 64);
        s0 += __shfl_xor(s0, 32, 64);
        if (lg == 0) {
            out1[n0w + lr] = s0;
            out2[n0w + lr] = s0;
        }
    }

    // ---- fused entropy: the last block to finish computes it ----
    __syncthreads();
    if (s_last) {
        float local = 0.0f;
        const float invn = 1.0f / (float)n_rows;
        if (t < NK) {
            int h = atomicAdd(&hist[t], 0);   // device-coherent read
            if (h > 0) {
                float p = (float)h * invn;
                local = p * logf(p);
            }
        }
        esq_lds[t] = local;                   // reuse as scratch (512 floats)
        __syncthreads();
        for (int s = 256; s >= 1; s >>= 1) {
            if (t < s) esq_lds[t] += esq_lds[t + s];
            __syncthreads();
        }
        if (t == 0) *ent = -esq_lds[0];
    }
}

extern "C" void kernel_launch(void* const* d_in, const int* in_sizes, int n_in,
                              void* d_out, int out_size, void* d_ws, size_t ws_size,
                              hipStream_t stream) {
    const float* x   = (const float*)d_in[0];   // (B,T,1,256) fp32
    const float* emb = (const float*)d_in[1];   // (1,512,256) fp32

    const int n_rows = in_sizes[0] / NV;        // 32768

    float* out0 = (float*)d_out;
    float* out1 = out0 + (size_t)n_rows * NV;
    float* out2 = out1 + n_rows;
    float* ent  = out2 + n_rows;

    // workspace: esq+2 (2KB) | hist (2KB) | counter (16B) | packed bf16 codebook (256KB)
    float* esq1   = (float*)d_ws;
    int* hist     = (int*)(esq1 + NK);
    int* counter  = hist + NK;
    u16* ehws     = (u16*)(counter + 4);

    vq_prepcvt<<<NK / 4, 256, 0, stream>>>(emb, esq1, ehws, hist, counter);
    vq_main<<<n_rows / BM, 512, 0, stream>>>(x, emb, ehws, esq1, hist, counter,
                                             out0, out1, out2, ent, n_rows);
}